// Round 3
// baseline (120.668 us; speedup 1.0000x reference)
//
#include <hip/hip_runtime.h>
#include <math.h>

#define BATCH 128
#define DIN   1024
#define DOUT  1024
#define NO    16   // o-rows per wave: 16 x 4KB = 64KB contiguous eps per wave

// Numerically stable softplus.
__device__ __forceinline__ float softplus_f(float v) {
    return fmaxf(v, 0.0f) + log1pf(__expf(-fabsf(v)));
}

// Round-to-nearest-even f32 -> bf16 (returned in low 16 bits).
__device__ __forceinline__ unsigned bf16_rne(float f) {
    unsigned u = __float_as_uint(f);
    return (u + 0x7FFFu + ((u >> 16) & 1u)) >> 16;
}

// Pack kernel: qm[o*DIN+i] = (bf16(softplus(rho[o,i])) << 16) | bf16(mu[o,i])
// Unpack in the hot loop is 1 shift + 1 and per element:
//   mu = as_float(w << 16); q = as_float(w & 0xffff0000).
// Also precomputes bsp[o] = softplus(brho[o]).
__global__ __launch_bounds__(256) void pack_qm_kernel(
    const float* __restrict__ wmu,
    const float* __restrict__ wrho,
    const float* __restrict__ brho,
    unsigned* __restrict__ qm,
    float* __restrict__ bsp)
{
    const int idx = blockIdx.x * 256 + threadIdx.x;  // float4 granularity, 262144 total
    const float4 m4 = reinterpret_cast<const float4*>(wmu)[idx];
    const float4 r4 = reinterpret_cast<const float4*>(wrho)[idx];
    uint4 w;
    w.x = (bf16_rne(softplus_f(r4.x)) << 16) | bf16_rne(m4.x);
    w.y = (bf16_rne(softplus_f(r4.y)) << 16) | bf16_rne(m4.y);
    w.z = (bf16_rne(softplus_f(r4.z)) << 16) | bf16_rne(m4.z);
    w.w = (bf16_rne(softplus_f(r4.w)) << 16) | bf16_rne(m4.w);
    reinterpret_cast<uint4*>(qm)[idx] = w;

    if (blockIdx.x < 4) {
        const int o = blockIdx.x * 256 + threadIdx.x;  // 0..1023
        bsp[o] = softplus_f(brho[o]);
    }
}

// Main kernel: one wave per (b, group of NO=16 o's).
// eps is read CONTIGUOUSLY (64KB run per wave, 256KB per block) — matching the
// access pattern that sustains 6.6 TB/s (fill-kernel evidence). x row lives in
// registers; (mu,q) stream as packed bf16 pairs from L2/L3 (qm is 4MB total).
__global__ __launch_bounds__(256) void bayes_main_kernel(
    const float* __restrict__ x,
    const unsigned* __restrict__ qm,
    const float* __restrict__ bmu,
    const float* __restrict__ bsp,
    const float* __restrict__ epsw,
    const float* __restrict__ epsb,
    float* __restrict__ out)
{
    const int wid  = blockIdx.x * 4 + (threadIdx.x >> 6);
    const int lane = threadIdx.x & 63;
    const int b  = wid >> 6;          // 0..127
    const int o0 = (wid & 63) * NO;   // 0..1008: consecutive waves -> contiguous eps

    // x[b,:] -> registers (16 floats/lane), from L2 (x is 512KB total).
    const float4* __restrict__ x4 = reinterpret_cast<const float4*>(x + (size_t)b * DIN);
    float xv[16];
    #pragma unroll
    for (int k = 0; k < 4; ++k) {
        const float4 t = x4[lane + (k << 6)];
        xv[4*k+0] = t.x; xv[4*k+1] = t.y; xv[4*k+2] = t.z; xv[4*k+3] = t.w;
    }

    const float4* __restrict__ e4base =
        reinterpret_cast<const float4*>(epsw + ((size_t)b * DOUT + o0) * DIN);
    const uint4* __restrict__ q4base =
        reinterpret_cast<const uint4*>(qm + (size_t)o0 * DIN);

    float acc[NO];

    #pragma unroll
    for (int oo = 0; oo < NO; ++oo) {
        const float4* __restrict__ e4 = e4base + (size_t)oo * (DIN / 4);
        const uint4*  __restrict__ q4 = q4base + (size_t)oo * (DIN / 4);
        float a = 0.0f;
        #pragma unroll
        for (int k = 0; k < 4; ++k) {
            const int idx = lane + (k << 6);
            const float4 ee = e4[idx];   // the HBM stream, contiguous
            const uint4  ww = q4[idx];   // packed (mu,q), L2/L3-hot
            const float mu0 = __uint_as_float(ww.x << 16);
            const float q0  = __uint_as_float(ww.x & 0xffff0000u);
            const float mu1 = __uint_as_float(ww.y << 16);
            const float q1  = __uint_as_float(ww.y & 0xffff0000u);
            const float mu2 = __uint_as_float(ww.z << 16);
            const float q2  = __uint_as_float(ww.z & 0xffff0000u);
            const float mu3 = __uint_as_float(ww.w << 16);
            const float q3  = __uint_as_float(ww.w & 0xffff0000u);
            a = fmaf(xv[4*k+0], fmaf(q0, ee.x, mu0), a);
            a = fmaf(xv[4*k+1], fmaf(q1, ee.y, mu1), a);
            a = fmaf(xv[4*k+2], fmaf(q2, ee.z, mu2), a);
            a = fmaf(xv[4*k+3], fmaf(q3, ee.w, mu3), a);
        }
        acc[oo] = a;
    }

    // 64-lane butterfly reductions.
    #pragma unroll
    for (int oo = 0; oo < NO; ++oo) {
        #pragma unroll
        for (int off = 32; off >= 1; off >>= 1)
            acc[oo] += __shfl_xor(acc[oo], off, 64);
    }

    if (lane == 0) {
        #pragma unroll
        for (int oo = 0; oo < NO; ++oo) {
            const int o = o0 + oo;
            const size_t row = (size_t)b * DOUT + o;
            out[row] = acc[oo] + fmaf(bsp[o], epsb[row], bmu[o]);
        }
    }
}

extern "C" void kernel_launch(void* const* d_in, const int* in_sizes, int n_in,
                              void* d_out, int out_size, void* d_ws, size_t ws_size,
                              hipStream_t stream) {
    const float* x    = (const float*)d_in[0];
    const float* wmu  = (const float*)d_in[1];
    const float* wrho = (const float*)d_in[2];
    const float* bmu  = (const float*)d_in[3];
    const float* brho = (const float*)d_in[4];
    const float* epsw = (const float*)d_in[5];
    const float* epsb = (const float*)d_in[6];
    float* out = (float*)d_out;

    unsigned* qm  = (unsigned*)d_ws;                       // 4 MB
    float*    bsp = (float*)((char*)d_ws + (size_t)DOUT * DIN * sizeof(unsigned)); // 4 KB

    // Pass 1: pack (mu, softplus(rho)) as bf16 pairs; softplus(brho).
    pack_qm_kernel<<<(DOUT * DIN / 4) / 256, 256, 0, stream>>>(wmu, wrho, brho, qm, bsp);

    // Pass 2: main stream. waves = BATCH * (DOUT/NO) = 128*64 = 8192; 4/block.
    bayes_main_kernel<<<8192 / 4, 256, 0, stream>>>(x, qm, bmu, bsp, epsw, epsb, out);
}